// Round 5
// baseline (969.381 us; speedup 1.0000x reference)
//
#include <hip/hip_runtime.h>
#include <math.h>

#define LN    524288        // signal length, 2^19
#define N1    512           // first-FFT length (column FFT)
#define N2    1024          // second-FFT length (row FFT)
#define NCH   129
#define DSR   80            // downsample rate
#define NOUT  6553          // output frames per channel
#define OB2   64            // outputs per IIR block
#define NBLK  103           // ceil(NOUT/OB2)
#define SPB   (OB2*DSR)     // 5120 samples per IIR block
#define TPW   20            // samples per thread in IIR
#define NPAIR 65            // ceil(129/2) channel pairs
#define KTAIL 48            // LN - NOUT*DSR

__device__ __forceinline__ float2 cmulf(float2 a, float2 b) {
    return make_float2(a.x*b.x - a.y*b.y, a.x*b.y + a.y*b.x);
}

// ---------------- pack real x into complex buffer ----------------
__global__ void pack_x(const float* __restrict__ x, float2* __restrict__ dst) {
    int i = blockIdx.x * 256 + threadIdx.x;
    dst[i] = make_float2(x[i], 0.f);
}

// ---------------- tiled complex transpose (forward path only) ----------------
__global__ void transpose_c(const float2* __restrict__ src, float2* __restrict__ dst,
                            int R, int Cc) {
    __shared__ float2 tile[32][33];
    size_t boff = (size_t)blockIdx.z * LN;
    src += boff; dst += boff;
    int x  = blockIdx.x * 32 + threadIdx.x;
    int y0 = blockIdx.y * 32 + threadIdx.y;
#pragma unroll
    for (int i = 0; i < 32; i += 8)
        tile[threadIdx.y + i][threadIdx.x] = src[(size_t)(y0 + i) * Cc + x];
    __syncthreads();
    int xo  = blockIdx.y * 32 + threadIdx.x;
    int yo0 = blockIdx.x * 32 + threadIdx.y;
#pragma unroll
    for (int i = 0; i < 32; i += 8)
        dst[(size_t)(yo0 + i) * R + xo] = tile[threadIdx.x][threadIdx.y + i];
}

// ---------------- LDS Stockham radix-2 row FFT, natural in/out, LDS twiddle table -----
template<int M, int SIGN, int TW>
__global__ __launch_bounds__(256) void fft_rows(const float2* __restrict__ src,
                                                float2* __restrict__ dst,
                                                int rows_per_batch) {
    __shared__ float2 ping[M];
    __shared__ float2 pong[M];
    __shared__ float2 twid[M];       // twid[Ns+jm] = e^{SIGN*i*pi*jm/Ns}
    size_t rowg = blockIdx.x;
    const float2* srow = src + rowg * M;
    float2* drow = dst + rowg * M;
    int row = (int)(rowg % (size_t)rows_per_batch);
    int t = threadIdx.x;
    for (int i = t; i < M; i += 256) {
        ping[i] = srow[i];
        if (i >= 1) {
            int h = 1 << (31 - __clz((unsigned)i));
            float ang = (float)SIGN * 3.14159265358979323846f * (float)(i - h) / (float)h;
            float s, c; __sincosf(ang, &s, &c);
            twid[i] = make_float2(c, s);
        }
    }
    __syncthreads();
    float2* a = ping;
    float2* b = pong;
    for (int Ns = 1; Ns < M; Ns <<= 1) {
        for (int j = t; j < M/2; j += 256) {
            int jm = j & (Ns - 1);
            float2 v0 = a[j];
            float2 v1 = a[j + M/2];
            float2 tw = twid[Ns + jm];
            float2 w = make_float2(v1.x*tw.x - v1.y*tw.y, v1.x*tw.y + v1.y*tw.x);
            int d0 = ((j & ~(Ns - 1)) << 1) | jm;
            b[d0]      = make_float2(v0.x + w.x, v0.y + w.y);
            b[d0 + Ns] = make_float2(v0.x - w.x, v0.y - w.y);
        }
        __syncthreads();
        float2* tmp = a; a = b; b = tmp;
    }
    if (TW) {
        const float c2pi = 6.28318530717958647692f / (float)LN;
        for (int i = t; i < M; i += 256) {
            float2 v = a[i];
            unsigned prod = ((unsigned)row * (unsigned)i) & (unsigned)(LN - 1);
            float ang = (float)SIGN * c2pi * (float)prod;
            float s, c;
            __sincosf(ang, &s, &c);
            drow[i] = make_float2(v.x*c - v.y*s, v.x*s + v.y*c);
        }
    } else {
        for (int i = t; i < M; i += 256) drow[i] = a[i];
    }
}

// ---------------- build paired Hermitian spectra W = Herm(Ya) + i*Herm(Yb) ----------------
// (round-1 validated version: pure streaming, full occupancy)
__global__ void build_w(const float* __restrict__ Hr, const float* __restrict__ Hi,
                        const float2* __restrict__ X, float2* __restrict__ W,
                        int pair0, int npairs) {
    size_t tid = (size_t)blockIdx.x * 256 + threadIdx.x;
    const size_t half = LN / 2;
    int pl = (int)(tid / half);
    if (pl >= npairs) return;
    unsigned k = (unsigned)(tid % half);
    int p = pair0 + pl;
    int ca = 2*p, cb = 2*p + 1;
    const float* Har = Hr + (size_t)ca * LN;
    const float* Hai = Hi + (size_t)ca * LN;
    const bool hasB = (cb < NCH);
    const float* Hbr = hasB ? (Hr + (size_t)cb * LN) : nullptr;
    const float* Hbi = hasB ? (Hi + (size_t)cb * LN) : nullptr;
    float2* Wp = W + (size_t)pl * LN;
    if (k == 0) {
        for (int kk = 0; kk < 2; kk++) {
            unsigned idx = kk ? (unsigned)half : 0u;
            float2 Xv = X[idx];
            float2 Ya = cmulf(make_float2(Har[idx], Hai[idx]), Xv);
            float br = 0.f;
            if (hasB) { float2 Yb = cmulf(make_float2(Hbr[idx], Hbi[idx]), Xv); br = Yb.x; }
            Wp[idx] = make_float2(Ya.x, br);
        }
        return;
    }
    unsigned kL = (unsigned)LN - k;
    float2 X1 = X[k], X2 = X[kL];
    float2 a1 = cmulf(make_float2(Har[k],  Hai[k]),  X1);
    float2 a2 = cmulf(make_float2(Har[kL], Hai[kL]), X2);
    float2 b1 = make_float2(0.f, 0.f), b2 = make_float2(0.f, 0.f);
    if (hasB) {
        b1 = cmulf(make_float2(Hbr[k],  Hbi[k]),  X1);
        b2 = cmulf(make_float2(Hbr[kL], Hbi[kL]), X2);
    }
    float yar = 0.5f*(a1.x + a2.x), yai = 0.5f*(a1.y - a2.y);
    float ybr = 0.5f*(b1.x + b2.x), ybi = 0.5f*(b1.y - b2.y);
    Wp[k]  = make_float2(yar - ybi, yai + ybr);
    float yar2 = 0.5f*(a2.x + a1.x), yai2 = 0.5f*(a2.y - a1.y);
    float ybr2 = 0.5f*(b2.x + b1.x), ybi2 = 0.5f*(b2.y - b1.y);
    Wp[kL] = make_float2(yar2 - ybi2, yai2 + ybr2);
}

// ---------------- column FFT: 16 consecutive cols per block, in-place DIF, sign +1 ----
// Reads W[r*1024+c], 512-pt FFT over r, four-step twiddle, writes D[jj*1024+c] IN PLACE
// (block owns its 16 columns exclusively; all reads complete before any write).
// LDS 66 KB -> 2 blocks x 1024 threads per CU (32 waves, 100% occupancy).
__global__ __launch_bounds__(1024) void kB(float2* __restrict__ D1) {
    __shared__ float sRe[16][513];
    __shared__ float sIm[16][513];
    __shared__ float2 twid[512];     // twid[h+q] = e^{+i pi q/h}
    int cg = blockIdx.x;             // column group 0..63
    int pl = blockIdx.y;             // pair within chunk
    float2* Dp = D1 + (size_t)pl * LN;
    unsigned c_base = 16u * cg;
    int t = threadIdx.x;

    if (t >= 1 && t < 512) {
        int h = 1 << (31 - __clz((unsigned)t));
        float ang = 3.14159265358979323846f * (float)(t - h) / (float)h;
        float s, c; __sincosf(ang, &s, &c);
        twid[t] = make_float2(c, s);
    }

    // ---- phase 1: load 16 columns (128B segments; r perm spreads banks) ----
#pragma unroll
    for (int i = 0; i < 8; i++) {
        int e = t + (i << 10);
        unsigned c_off = (unsigned)(e & 15);
        unsigned idx   = (unsigned)(e >> 4);        // 0..511
        unsigned r = (idx & 0x1E0u) | ((idx & 3u) << 3) | ((idx >> 2) & 7u);
        float2 v = Dp[(size_t)r * N2 + c_base + c_off];
        sRe[c_off][r] = v.x;
        sIm[c_off][r] = v.y;
    }
    __syncthreads();

    // ---- phase 2: 9-stage in-place radix-2 DIF over rows, lane-fast over 16 cols ----
    int cc   = t & 15;
    int jgrp = t >> 4;               // 0..63
    for (int h = 256; h >= 1; h >>= 1) {
#pragma unroll
        for (int i = 0; i < 4; i++) {
            int j = jgrp + (i << 6);             // 0..255
            int q = j & (h - 1);
            int base = ((j & ~(h - 1)) << 1) | q;
            float2 w = twid[h + q];
            float are = sRe[cc][base],     aim = sIm[cc][base];
            float bre = sRe[cc][base + h], bim = sIm[cc][base + h];
            sRe[cc][base] = are + bre;  sIm[cc][base] = aim + bim;
            float dre = are - bre, dim = aim - bim;
            sRe[cc][base + h] = dre*w.x - dim*w.y;
            sIm[cc][base + h] = dre*w.y + dim*w.x;
        }
        __syncthreads();
    }

    // ---- phase 3: bitrev row, four-step twiddle, coalesced in-place write ----
    const float c2pi = 6.28318530717958647692f / (float)LN;
    unsigned truec = c_base + (unsigned)(t & 15);
    int pos0 = t >> 4;               // 0..63
#pragma unroll
    for (int i = 0; i < 8; i++) {
        int pos = pos0 + (i << 6);               // 0..511
        unsigned jj = __brev((unsigned)pos) >> 23;   // bitrev9
        float re = sRe[t & 15][pos], im = sIm[t & 15][pos];
        unsigned prod = (jj * truec) & (unsigned)(LN - 1);
        float ang = c2pi * (float)prod;
        float s, c;
        __sincosf(ang, &s, &c);
        Dp[(size_t)jj * N2 + truec] = make_float2(re*c - im*s, re*s + im*c);
    }
}

// ---------------- final transpose of IFFT + 1/L scale + power-law ----------------
__global__ void ifft_finish(const float2* __restrict__ src, float* __restrict__ comp,
                            const float* __restrict__ alpha_comp, int pair0) {
    __shared__ float2 tile[32][33];
    int pl = blockIdx.z;
    int p = pair0 + pl;
    int ca = 2*p, cb = 2*p + 1;
    const float2* s = src + (size_t)pl * LN;
    int x  = blockIdx.x * 32 + threadIdx.x;   // col (m) in [0,1024)
    int y0 = blockIdx.y * 32 + threadIdx.y;   // row (j) in [0,512)
#pragma unroll
    for (int i = 0; i < 32; i += 8)
        tile[threadIdx.y + i][threadIdx.x] = s[(size_t)(y0 + i) * N2 + x];
    __syncthreads();
    float aa = alpha_comp[ca];
    float ab = (cb < NCH) ? alpha_comp[cb] : 1.f;
    const float invL = 1.f / (float)LN;
    int xo  = blockIdx.y * 32 + threadIdx.x;  // j
    int yo0 = blockIdx.x * 32 + threadIdx.y;  // m
#pragma unroll
    for (int i = 0; i < 32; i += 8) {
        int yo = yo0 + i;
        float2 v = tile[threadIdx.x][threadIdx.y + i];
        size_t n = (size_t)yo * N1 + xo;      // n = 512*m + j
        float ra = v.x * invL;
        float rb = v.y * invL;
        comp[(size_t)ca * LN + n] = copysignf(powf(fabsf(ra), aa), ra);
        if (cb < NCH)
            comp[(size_t)cb * LN + n] = copysignf(powf(fabsf(rb), ab), rb);
    }
}

// ---------------- leaky IIR part 1: thread-per-20-samples + affine shuffle scan ----------
__global__ __launch_bounds__(256) void iir_part1(
    const float* __restrict__ comp, const float* __restrict__ alpha_leak,
    const float* __restrict__ li_kernel, float* __restrict__ out,
    float* __restrict__ carryOut) {
    __shared__ float win[SPB + SPB/TPW];   // pad every 20 (stride 21)
    __shared__ float wv[4], wg[4];
    int blk = blockIdx.x;
    int c = blockIdx.y;
    int t = threadIdx.x;
    float alpha = alpha_leak[0];
    float k0 = li_kernel[0], k1 = li_kernel[1];
    int base = blk * SPB;
    const int cap = NOUT * DSR;   // 524240
    const float* c0 = comp + (size_t)c * LN;
    const float* c1 = (c + 1 < NCH) ? comp + (size_t)(c + 1) * LN : nullptr;
    for (int i = t; i < SPB; i += 256) {
        int g = base + i;
        float v = 0.f;
        if (g < cap) {
            float u0 = c0[g];
            float u1 = c1 ? c1[g] : 0.f;
            v = fmaxf(k0 * u0 + k1 * u1, 0.f);
        }
        win[i + i / TPW] = v;
    }
    __syncthreads();
    float v = 0.f;
    int lbase = 21 * t;
#pragma unroll
    for (int i = 0; i < TPW; i++)
        v = fmaf(alpha, v, win[lbase + i]);
    float g = powf(alpha, (float)TPW);
    int lid = t & 63, wid = t >> 6;
#pragma unroll
    for (int d = 1; d < 64; d <<= 1) {
        float pv = __shfl_up(v, d);
        float pg = __shfl_up(g, d);
        if (lid >= d) { v = fmaf(g, pv, v); g = g * pg; }
    }
    if (lid == 63) { wv[wid] = v; wg[wid] = g; }
    __syncthreads();
    float cv = 0.f;
#pragma unroll
    for (int w = 0; w < 3; w++)
        if (w < wid) cv = wv[w] + wg[w] * cv;
    float vf = fmaf(g, cv, v);
    int nact = NOUT - blk * OB2; if (nact > OB2) nact = OB2;
    if ((t & 3) == 3) {
        int o = t >> 2;
        if (o < nact)
            out[(size_t)c * NOUT + blk * OB2 + o] = vf;
    }
    if (t == 4 * nact - 1)
        carryOut[c * NBLK + blk] = vf;
}

// ---------------- IIR part 2: per-channel carries (incl. circular wrap) ----------------
__global__ void iir_part2(const float* __restrict__ comp, const float* __restrict__ alpha_leak,
                          const float* __restrict__ li_kernel,
                          const float* __restrict__ carryOut, float* __restrict__ D) {
    int c = threadIdx.x;
    if (c >= NCH) return;
    float alpha = alpha_leak[0];
    float k0 = li_kernel[0], k1 = li_kernel[1];
    const float* c0 = comp + (size_t)c * LN;
    const float* c1 = (c + 1 < NCH) ? comp + (size_t)(c + 1) * LN : nullptr;
    float tail = 0.f, ap = 1.f;
    for (int j = 0; j < KTAIL; j++) {
        int g = LN - 1 - j;
        float u0 = c0[g];
        float u1 = c1 ? c1[g] : 0.f;
        float v = k0 * u0 + k1 * u1; v = v > 0.f ? v : 0.f;
        tail += ap * v;
        ap *= alpha;
    }
    float D0 = tail + ap * carryOut[c * NBLK + (NBLK - 1)]
             + powf(alpha, (float)(KTAIL + 2000)) * carryOut[c * NBLK + (NBLK - 2)];
    D[c * NBLK + 0] = D0;
    for (int b = 1; b < NBLK; b++)
        D[c * NBLK + b] = carryOut[c * NBLK + b - 1];
}

// ---------------- IIR part 3: add decayed carry into each output ----------------
__global__ void iir_part3(const float* __restrict__ D, const float* __restrict__ alpha_leak,
                          float* __restrict__ out) {
    int idx = blockIdx.x * 256 + threadIdx.x;
    if (idx >= NCH * NOUT) return;
    int c = idx / NOUT, m = idx - c * NOUT;
    int b = m / OB2, o = m - b * OB2;
    float alpha = alpha_leak[0];
    float beta = powf(alpha, (float)DSR);
    float dec = powf(beta, (float)(o + 1));
    out[idx] += dec * D[c * NBLK + b];
}

extern "C" void kernel_launch(void* const* d_in, const int* in_sizes, int n_in,
                              void* d_out, int out_size, void* d_ws, size_t ws_size,
                              hipStream_t stream) {
    const float* x  = (const float*)d_in[0];
    const float* Hr = (const float*)d_in[1];
    const float* Hi = (const float*)d_in[2];
    const float* ac = (const float*)d_in[3];
    const float* al = (const float*)d_in[4];
    const float* li = (const float*)d_in[5];
    float* out = (float*)d_out;

    char* ws = (char*)d_ws;
    size_t off = 0;
    auto alloc = [&](size_t bytes) -> void* {
        void* p = ws + off;
        off += (bytes + 255) & ~(size_t)255;
        return p;
    };
    float2* Xf     = (float2*)alloc((size_t)LN * sizeof(float2));
    float*  comp   = (float*) alloc((size_t)NCH * LN * sizeof(float));
    float*  cOut   = (float*) alloc((size_t)NCH * NBLK * sizeof(float));
    float*  Dbuf   = (float*) alloc((size_t)NCH * NBLK * sizeof(float));
    size_t remain = (ws_size > off) ? (ws_size - off) : 0;
    int chunk = (int)(remain / ((size_t)LN * sizeof(float2)));
    if (chunk > NPAIR) chunk = NPAIR;
    if (chunk < 2)     chunk = 2;
    float2* bufA = (float2*)alloc((size_t)chunk * LN * sizeof(float2));

    dim3 tb(32, 8, 1);

    // ---- forward FFT of x (four-step with transposes; small, one signal) ----
    float2* fA = bufA;
    float2* fB = bufA + LN;
    pack_x<<<LN / 256, 256, 0, stream>>>(x, fA);
    transpose_c<<<dim3(N2/32, N1/32, 1), tb, 0, stream>>>(fA, fB, N1, N2);
    fft_rows<N1, -1, 1><<<N2, 256, 0, stream>>>(fB, fB, N2);
    transpose_c<<<dim3(N1/32, N2/32, 1), tb, 0, stream>>>(fB, fA, N2, N1);
    fft_rows<N2, -1, 0><<<N1, 256, 0, stream>>>(fA, fA, N1);
    transpose_c<<<dim3(N2/32, N1/32, 1), tb, 0, stream>>>(fA, Xf, N1, N2);

    // ---- batched inverse FFTs: build_w -> colFFT(in-place) -> rowFFT -> finish ----
    for (int ci = 0; ci < NPAIR; ci += chunk) {
        int np = NPAIR - ci; if (np > chunk) np = chunk;
        build_w<<<(np * (LN/2)) / 256, 256, 0, stream>>>(Hr, Hi, Xf, bufA, ci, np);
        kB<<<dim3(64, np), 1024, 0, stream>>>(bufA);
        fft_rows<N2, 1, 0><<<N1 * np, 256, 0, stream>>>(bufA, bufA, N1);
        ifft_finish<<<dim3(N2/32, N1/32, np), tb, 0, stream>>>(bufA, comp, ac, ci);
    }

    // ---- leaky integration (time-domain, exact to fp precision) + downsample ----
    iir_part1<<<dim3(NBLK, NCH, 1), 256, 0, stream>>>(comp, al, li, out, cOut);
    iir_part2<<<1, 256, 0, stream>>>(comp, al, li, cOut, Dbuf);
    iir_part3<<<(NCH * NOUT + 255) / 256, 256, 0, stream>>>(Dbuf, al, out);
}

// Round 7
// 826.003 us; speedup vs baseline: 1.1736x; 1.1736x over previous
//
#include <hip/hip_runtime.h>
#include <math.h>

#define LN    524288        // signal length, 2^19
#define N1    512           // first-FFT length (column FFT)
#define N2    1024          // second-FFT length (row FFT)
#define NCH   129
#define DSR   80            // downsample rate
#define NOUT  6553          // output frames per channel
#define OB2   64            // outputs per IIR block
#define NBLK  103           // ceil(NOUT/OB2)
#define SPB   (OB2*DSR)     // 5120 samples per IIR block
#define TPW   20            // samples per thread in IIR
#define NPAIR 65            // ceil(129/2) channel pairs
#define KTAIL 48            // LN - NOUT*DSR

__device__ __forceinline__ float2 cmulf(float2 a, float2 b) {
    return make_float2(a.x*b.x - a.y*b.y, a.x*b.y + a.y*b.x);
}

// fast |x|^a * sign(x): hardware log2/exp2 (x=0 -> -inf -> 0, correct)
__device__ __forceinline__ float powsign(float x, float a) {
    float m = __builtin_amdgcn_exp2f(a * __builtin_amdgcn_logf(fabsf(x)));
    return copysignf(m, x);
}

// ---------------- pack real x into complex buffer ----------------
__global__ void pack_x(const float* __restrict__ x, float2* __restrict__ dst) {
    int i = blockIdx.x * 256 + threadIdx.x;
    dst[i] = make_float2(x[i], 0.f);
}

// ---------------- tiled complex transpose (forward path only) ----------------
__global__ void transpose_c(const float2* __restrict__ src, float2* __restrict__ dst,
                            int R, int Cc) {
    __shared__ float2 tile[32][33];
    size_t boff = (size_t)blockIdx.z * LN;
    src += boff; dst += boff;
    int x  = blockIdx.x * 32 + threadIdx.x;
    int y0 = blockIdx.y * 32 + threadIdx.y;
#pragma unroll
    for (int i = 0; i < 32; i += 8)
        tile[threadIdx.y + i][threadIdx.x] = src[(size_t)(y0 + i) * Cc + x];
    __syncthreads();
    int xo  = blockIdx.y * 32 + threadIdx.x;
    int yo0 = blockIdx.x * 32 + threadIdx.y;
#pragma unroll
    for (int i = 0; i < 32; i += 8)
        dst[(size_t)(yo0 + i) * R + xo] = tile[threadIdx.x][threadIdx.y + i];
}

// ---------------- LDS Stockham radix-2 row FFT, natural in/out, LDS twiddle table -----
template<int M, int SIGN, int TW>
__global__ __launch_bounds__(256) void fft_rows(const float2* __restrict__ src,
                                                float2* __restrict__ dst,
                                                int rows_per_batch) {
    __shared__ float2 ping[M];
    __shared__ float2 pong[M];
    __shared__ float2 twid[M];       // twid[Ns+jm] = e^{SIGN*i*pi*jm/Ns}
    size_t rowg = blockIdx.x;
    const float2* srow = src + rowg * M;
    float2* drow = dst + rowg * M;
    int row = (int)(rowg % (size_t)rows_per_batch);
    int t = threadIdx.x;
    for (int i = t; i < M; i += 256) {
        ping[i] = srow[i];
        if (i >= 1) {
            int h = 1 << (31 - __clz((unsigned)i));
            float ang = (float)SIGN * 3.14159265358979323846f * (float)(i - h) / (float)h;
            float s, c; __sincosf(ang, &s, &c);
            twid[i] = make_float2(c, s);
        }
    }
    __syncthreads();
    float2* a = ping;
    float2* b = pong;
    for (int Ns = 1; Ns < M; Ns <<= 1) {
        for (int j = t; j < M/2; j += 256) {
            int jm = j & (Ns - 1);
            float2 v0 = a[j];
            float2 v1 = a[j + M/2];
            float2 tw = twid[Ns + jm];
            float2 w = make_float2(v1.x*tw.x - v1.y*tw.y, v1.x*tw.y + v1.y*tw.x);
            int d0 = ((j & ~(Ns - 1)) << 1) | jm;
            b[d0]      = make_float2(v0.x + w.x, v0.y + w.y);
            b[d0 + Ns] = make_float2(v0.x - w.x, v0.y - w.y);
        }
        __syncthreads();
        float2* tmp = a; a = b; b = tmp;
    }
    if (TW) {
        const float c2pi = 6.28318530717958647692f / (float)LN;
        for (int i = t; i < M; i += 256) {
            float2 v = a[i];
            unsigned prod = ((unsigned)row * (unsigned)i) & (unsigned)(LN - 1);
            float ang = (float)SIGN * c2pi * (float)prod;
            float s, c;
            __sincosf(ang, &s, &c);
            drow[i] = make_float2(v.x*c - v.y*s, v.x*s + v.y*c);
        }
    } else {
        for (int i = t; i < M; i += 256) drow[i] = a[i];
    }
}

// ---------------- build paired Hermitian spectra W = Herm(Ya) + i*Herm(Yb) ----------------
__global__ void build_w(const float* __restrict__ Hr, const float* __restrict__ Hi,
                        const float2* __restrict__ X, float2* __restrict__ W,
                        int pair0, int npairs) {
    size_t tid = (size_t)blockIdx.x * 256 + threadIdx.x;
    const size_t half = LN / 2;
    int pl = (int)(tid / half);
    if (pl >= npairs) return;
    unsigned k = (unsigned)(tid % half);
    int p = pair0 + pl;
    int ca = 2*p, cb = 2*p + 1;
    const float* Har = Hr + (size_t)ca * LN;
    const float* Hai = Hi + (size_t)ca * LN;
    const bool hasB = (cb < NCH);
    const float* Hbr = hasB ? (Hr + (size_t)cb * LN) : nullptr;
    const float* Hbi = hasB ? (Hi + (size_t)cb * LN) : nullptr;
    float2* Wp = W + (size_t)pl * LN;
    if (k == 0) {
        for (int kk = 0; kk < 2; kk++) {
            unsigned idx = kk ? (unsigned)half : 0u;
            float2 Xv = X[idx];
            float2 Ya = cmulf(make_float2(Har[idx], Hai[idx]), Xv);
            float br = 0.f;
            if (hasB) { float2 Yb = cmulf(make_float2(Hbr[idx], Hbi[idx]), Xv); br = Yb.x; }
            Wp[idx] = make_float2(Ya.x, br);
        }
        return;
    }
    unsigned kL = (unsigned)LN - k;
    float2 X1 = X[k], X2 = X[kL];
    float2 a1 = cmulf(make_float2(Har[k],  Hai[k]),  X1);
    float2 a2 = cmulf(make_float2(Har[kL], Hai[kL]), X2);
    float2 b1 = make_float2(0.f, 0.f), b2 = make_float2(0.f, 0.f);
    if (hasB) {
        b1 = cmulf(make_float2(Hbr[k],  Hbi[k]),  X1);
        b2 = cmulf(make_float2(Hbr[kL], Hbi[kL]), X2);
    }
    float yar = 0.5f*(a1.x + a2.x), yai = 0.5f*(a1.y - a2.y);
    float ybr = 0.5f*(b1.x + b2.x), ybi = 0.5f*(b1.y - b2.y);
    Wp[k]  = make_float2(yar - ybi, yai + ybr);
    float yar2 = 0.5f*(a2.x + a1.x), yai2 = 0.5f*(a2.y - a1.y);
    float ybr2 = 0.5f*(b2.x + b1.x), ybi2 = 0.5f*(b2.y - b1.y);
    Wp[kL] = make_float2(yar2 - ybi2, yai2 + ybr2);
}

// ---------------- column FFT: 16 consecutive cols per block, in-place DIF, sign +1 ----
__global__ __launch_bounds__(1024) void kB(float2* __restrict__ D1) {
    __shared__ float sRe[16][513];
    __shared__ float sIm[16][513];
    __shared__ float2 twid[512];     // twid[h+q] = e^{+i pi q/h}
    int cg = blockIdx.x;             // column group 0..63
    int pl = blockIdx.y;             // pair within chunk
    float2* Dp = D1 + (size_t)pl * LN;
    unsigned c_base = 16u * cg;
    int t = threadIdx.x;

    if (t >= 1 && t < 512) {
        int h = 1 << (31 - __clz((unsigned)t));
        float ang = 3.14159265358979323846f * (float)(t - h) / (float)h;
        float s, c; __sincosf(ang, &s, &c);
        twid[t] = make_float2(c, s);
    }

    // ---- phase 1: load 16 columns (128B segments; r perm spreads banks) ----
#pragma unroll
    for (int i = 0; i < 8; i++) {
        int e = t + (i << 10);
        unsigned c_off = (unsigned)(e & 15);
        unsigned idx   = (unsigned)(e >> 4);        // 0..511
        unsigned r = (idx & 0x1E0u) | ((idx & 3u) << 3) | ((idx >> 2) & 7u);
        float2 v = Dp[(size_t)r * N2 + c_base + c_off];
        sRe[c_off][r] = v.x;
        sIm[c_off][r] = v.y;
    }
    __syncthreads();

    // ---- phase 2: 9-stage in-place radix-2 DIF over rows, lane-fast over 16 cols ----
    int cc   = t & 15;
    int jgrp = t >> 4;               // 0..63
    for (int h = 256; h >= 1; h >>= 1) {
#pragma unroll
        for (int i = 0; i < 4; i++) {
            int j = jgrp + (i << 6);             // 0..255
            int q = j & (h - 1);
            int base = ((j & ~(h - 1)) << 1) | q;
            float2 w = twid[h + q];
            float are = sRe[cc][base],     aim = sIm[cc][base];
            float bre = sRe[cc][base + h], bim = sIm[cc][base + h];
            sRe[cc][base] = are + bre;  sIm[cc][base] = aim + bim;
            float dre = are - bre, dim = aim - bim;
            sRe[cc][base + h] = dre*w.x - dim*w.y;
            sIm[cc][base + h] = dre*w.y + dim*w.x;
        }
        __syncthreads();
    }

    // ---- phase 3: bitrev row, four-step twiddle, coalesced in-place write ----
    const float c2pi = 6.28318530717958647692f / (float)LN;
    unsigned truec = c_base + (unsigned)(t & 15);
    int pos0 = t >> 4;               // 0..63
#pragma unroll
    for (int i = 0; i < 8; i++) {
        int pos = pos0 + (i << 6);               // 0..511
        unsigned jj = __brev((unsigned)pos) >> 23;   // bitrev9
        float re = sRe[t & 15][pos], im = sIm[t & 15][pos];
        unsigned prod = (jj * truec) & (unsigned)(LN - 1);
        float ang = c2pi * (float)prod;
        float s, c;
        __sincosf(ang, &s, &c);
        Dp[(size_t)jj * N2 + truec] = make_float2(re*c - im*s, re*s + im*c);
    }
}

// ---------------- final transpose of IFFT + 1/L scale + power-law (fast pow) ----------
__global__ void ifft_finish(const float2* __restrict__ src, float* __restrict__ comp,
                            const float* __restrict__ alpha_comp, int pair0) {
    __shared__ float2 tile[32][33];
    int pl = blockIdx.z;
    int p = pair0 + pl;
    int ca = 2*p, cb = 2*p + 1;
    const float2* s = src + (size_t)pl * LN;
    int x  = blockIdx.x * 32 + threadIdx.x;   // col (m) in [0,1024)
    int y0 = blockIdx.y * 32 + threadIdx.y;   // row (j) in [0,512)
#pragma unroll
    for (int i = 0; i < 32; i += 8)
        tile[threadIdx.y + i][threadIdx.x] = s[(size_t)(y0 + i) * N2 + x];
    __syncthreads();
    float aa = alpha_comp[ca];
    float ab = (cb < NCH) ? alpha_comp[cb] : 1.f;
    const float invL = 1.f / (float)LN;
    int xo  = blockIdx.y * 32 + threadIdx.x;  // j
    int yo0 = blockIdx.x * 32 + threadIdx.y;  // m
#pragma unroll
    for (int i = 0; i < 32; i += 8) {
        int yo = yo0 + i;
        float2 v = tile[threadIdx.x][threadIdx.y + i];
        size_t n = (size_t)yo * N1 + xo;      // n = 512*m + j
        float ra = v.x * invL;
        float rb = v.y * invL;
        comp[(size_t)ca * LN + n] = powsign(ra, aa);
        if (cb < NCH)
            comp[(size_t)cb * LN + n] = powsign(rb, ab);
    }
}

// ---------------- leaky IIR part 1: thread-per-20-samples + affine shuffle scan ----------
__global__ __launch_bounds__(256) void iir_part1(
    const float* __restrict__ comp, const float* __restrict__ alpha_leak,
    const float* __restrict__ li_kernel, float* __restrict__ out,
    float* __restrict__ carryOut) {
    __shared__ float win[SPB + SPB/TPW];   // pad every 20 (stride 21)
    __shared__ float wv[4], wg[4];
    int blk = blockIdx.x;
    int c = blockIdx.y;
    int t = threadIdx.x;
    float alpha = alpha_leak[0];
    float k0 = li_kernel[0], k1 = li_kernel[1];
    int base = blk * SPB;
    const int cap = NOUT * DSR;   // 524240
    const float* c0 = comp + (size_t)c * LN;
    const float* c1 = (c + 1 < NCH) ? comp + (size_t)(c + 1) * LN : nullptr;
    for (int i = t; i < SPB; i += 256) {
        int g = base + i;
        float v = 0.f;
        if (g < cap) {
            float u0 = c0[g];
            float u1 = c1 ? c1[g] : 0.f;
            v = fmaxf(k0 * u0 + k1 * u1, 0.f);
        }
        win[i + i / TPW] = v;
    }
    __syncthreads();
    float v = 0.f;
    int lbase = 21 * t;
#pragma unroll
    for (int i = 0; i < TPW; i++)
        v = fmaf(alpha, v, win[lbase + i]);
    float g = powf(alpha, (float)TPW);
    int lid = t & 63, wid = t >> 6;
#pragma unroll
    for (int d = 1; d < 64; d <<= 1) {
        float pv = __shfl_up(v, d);
        float pg = __shfl_up(g, d);
        if (lid >= d) { v = fmaf(g, pv, v); g = g * pg; }
    }
    if (lid == 63) { wv[wid] = v; wg[wid] = g; }
    __syncthreads();
    float cv = 0.f;
#pragma unroll
    for (int w = 0; w < 3; w++)
        if (w < wid) cv = wv[w] + wg[w] * cv;
    float vf = fmaf(g, cv, v);
    int nact = NOUT - blk * OB2; if (nact > OB2) nact = OB2;
    if ((t & 3) == 3) {
        int o = t >> 2;
        if (o < nact)
            out[(size_t)c * NOUT + blk * OB2 + o] = vf;
    }
    if (t == 4 * nact - 1)
        carryOut[c * NBLK + blk] = vf;
}

// ---------------- IIR part 2: per-channel carries (incl. circular wrap) ----------------
__global__ void iir_part2(const float* __restrict__ comp, const float* __restrict__ alpha_leak,
                          const float* __restrict__ li_kernel,
                          const float* __restrict__ carryOut, float* __restrict__ D) {
    int c = threadIdx.x;
    if (c >= NCH) return;
    float alpha = alpha_leak[0];
    float k0 = li_kernel[0], k1 = li_kernel[1];
    const float* c0 = comp + (size_t)c * LN;
    const float* c1 = (c + 1 < NCH) ? comp + (size_t)(c + 1) * LN : nullptr;
    float tail = 0.f, ap = 1.f;
    for (int j = 0; j < KTAIL; j++) {
        int g = LN - 1 - j;
        float u0 = c0[g];
        float u1 = c1 ? c1[g] : 0.f;
        float v = k0 * u0 + k1 * u1; v = v > 0.f ? v : 0.f;
        tail += ap * v;
        ap *= alpha;
    }
    float D0 = tail + ap * carryOut[c * NBLK + (NBLK - 1)]
             + powf(alpha, (float)(KTAIL + 2000)) * carryOut[c * NBLK + (NBLK - 2)];
    D[c * NBLK + 0] = D0;
    for (int b = 1; b < NBLK; b++)
        D[c * NBLK + b] = carryOut[c * NBLK + b - 1];
}

// ---------------- IIR part 3: add decayed carry into each output ----------------
__global__ void iir_part3(const float* __restrict__ D, const float* __restrict__ alpha_leak,
                          float* __restrict__ out) {
    int idx = blockIdx.x * 256 + threadIdx.x;
    if (idx >= NCH * NOUT) return;
    int c = idx / NOUT, m = idx - c * NOUT;
    int b = m / OB2, o = m - b * OB2;
    float alpha = alpha_leak[0];
    float beta = powf(alpha, (float)DSR);
    float dec = powf(beta, (float)(o + 1));
    out[idx] += dec * D[c * NBLK + b];
}

extern "C" void kernel_launch(void* const* d_in, const int* in_sizes, int n_in,
                              void* d_out, int out_size, void* d_ws, size_t ws_size,
                              hipStream_t stream) {
    const float* x  = (const float*)d_in[0];
    const float* Hr = (const float*)d_in[1];
    const float* Hi = (const float*)d_in[2];
    const float* ac = (const float*)d_in[3];
    const float* al = (const float*)d_in[4];
    const float* li = (const float*)d_in[5];
    float* out = (float*)d_out;

    char* ws = (char*)d_ws;
    size_t off = 0;
    auto alloc = [&](size_t bytes) -> void* {
        void* p = ws + off;
        off += (bytes + 255) & ~(size_t)255;
        return p;
    };
    float2* Xf     = (float2*)alloc((size_t)LN * sizeof(float2));
    float*  comp   = (float*) alloc((size_t)NCH * LN * sizeof(float));
    float*  cOut   = (float*) alloc((size_t)NCH * NBLK * sizeof(float));
    float*  Dbuf   = (float*) alloc((size_t)NCH * NBLK * sizeof(float));
    size_t remain = (ws_size > off) ? (ws_size - off) : 0;
    int chunk = (int)(remain / ((size_t)LN * sizeof(float2)));
    if (chunk > NPAIR) chunk = NPAIR;
    if (chunk < 2)     chunk = 2;
    float2* bufA = (float2*)alloc((size_t)chunk * LN * sizeof(float2));

    dim3 tb(32, 8, 1);

    // ---- forward FFT of x (four-step with transposes; small, one signal) ----
    float2* fA = bufA;
    float2* fB = bufA + LN;
    pack_x<<<LN / 256, 256, 0, stream>>>(x, fA);
    transpose_c<<<dim3(N2/32, N1/32, 1), tb, 0, stream>>>(fA, fB, N1, N2);
    fft_rows<N1, -1, 1><<<N2, 256, 0, stream>>>(fB, fB, N2);
    transpose_c<<<dim3(N1/32, N2/32, 1), tb, 0, stream>>>(fB, fA, N2, N1);
    fft_rows<N2, -1, 0><<<N1, 256, 0, stream>>>(fA, fA, N1);
    transpose_c<<<dim3(N2/32, N1/32, 1), tb, 0, stream>>>(fA, Xf, N1, N2);

    // ---- batched inverse FFTs: build_w -> colFFT(in-place) -> rowFFT -> finish ----
    for (int ci = 0; ci < NPAIR; ci += chunk) {
        int np = NPAIR - ci; if (np > chunk) np = chunk;
        build_w<<<(np * (LN/2)) / 256, 256, 0, stream>>>(Hr, Hi, Xf, bufA, ci, np);
        kB<<<dim3(64, np), 1024, 0, stream>>>(bufA);
        fft_rows<N2, 1, 0><<<N1 * np, 256, 0, stream>>>(bufA, bufA, N1);
        ifft_finish<<<dim3(N2/32, N1/32, np), tb, 0, stream>>>(bufA, comp, ac, ci);
    }

    // ---- leaky integration (time-domain, exact to fp precision) + downsample ----
    iir_part1<<<dim3(NBLK, NCH, 1), 256, 0, stream>>>(comp, al, li, out, cOut);
    iir_part2<<<1, 256, 0, stream>>>(comp, al, li, cOut, Dbuf);
    iir_part3<<<(NCH * NOUT + 255) / 256, 256, 0, stream>>>(Dbuf, al, out);
}